// Round 4
// baseline (991.328 us; speedup 1.0000x reference)
//
#include <hip/hip_runtime.h>
#include <stdint.h>

// 25-qubit, 8-layer RY + CNOT-chain circuit, output <Z_q0>.
// CNOT chains deferred into a GF(2) change-of-basis; only 200 RYs touch the
// 2^25-float state (d_ws, 128 MiB, L3-resident). Masks constexpr; kernels
// templated on layer. Dual-basis identity (F_j . M_i = delta_ij) collapses
// all per-pair sign patterns to one sign bit per dim per thread.
// Round 4: persistent blocks (grid 256 = 1 block/CU), each sweeping 4 tiles
// with cross-tile software pipelining — next tile's global loads issued
// before the current tile's barrier-fenced exchange phases, so HBM streams
// while VALU computes. Stores of tile i drain during R0 of tile i+1.

#define NQ 25
#define DEPTH 8

struct MaskSet {
  uint32_t M[DEPTH][NQ];   // M[l][b] = column b of W_l (pairing masks)
  uint32_t F[DEPTH][NQ];   // F[l][b] = row b of W_l^-1 (orientation functionals)
  uint32_t fz;             // final Z functional (row 24 of W_8^-1)
};

__host__ __device__ constexpr MaskSet buildMasks() {
  MaskSet r{};
  uint32_t col[NQ] = {}, inv[NQ] = {};
  for (int j = 0; j < NQ; ++j) { col[j] = 1u << j; inv[j] = 1u << j; }
  for (int l = 0; l < DEPTH; ++l) {
    for (int b = 0; b < NQ; ++b) { r.M[l][b] = col[b]; r.F[l][b] = inv[b]; }
    for (int w = 0; w < NQ - 1; ++w) {   // CNOT chain of layer l
      const int cb = 24 - w, tb = 23 - w;
      col[cb] ^= col[tb];
      inv[tb] ^= inv[cb];
    }
  }
  r.fz = inv[24];
  return r;
}

constexpr MaskSet MK = buildMasks();

// Swizzle: XOR low slot bits (2..4) with owner bits (5..7). Linear over GF(2),
// 16B groups preserved -> b128-friendly, conflict-free for both segment-major
// (b128) and low-5-bijective (b32) patterns.
__host__ __device__ constexpr uint32_t cswz(uint32_t a) { return a ^ ((a >> 3) & 28u); }

__host__ __device__ constexpr uint32_t kxorB(int L, int d0, uint32_t y) {
  uint32_t a = 0;
  for (int i = 0; i < 5; ++i) if ((y >> i) & 1u) a ^= MK.M[L][d0 + i];
  return a;
}

__host__ __device__ constexpr uint32_t cpar(uint32_t x) {
  uint32_t p = 0;
  for (int i = 0; i < 32; ++i) p ^= (x >> i) & 1u;
  return p;
}

__global__ void kprep(const float* __restrict__ theta, float* __restrict__ trig,
                      float* __restrict__ outp)
{
  int t = threadIdx.x;
  if (t == 0) outp[0] = 0.0f;
  if (t < 200) {
    int l = t / 25, b = t % 25;            // b = bit position, qubit w = 24-b
    float th = theta[l * 25 + (24 - b)] * 0.5f;
    trig[2 * t]     = cosf(th);
    trig[2 * t + 1] = sinf(th);
  }
}

// ---- passB tail: R0 (dims 0..4, v in tile-address order) -> LDS -> R1 ->
//      LDS -> R2 -> direct global store. Ends with a barrier after the R2
//      LDS reads so the caller may immediately reuse the LDS buffer.
template<int L>
__device__ __forceinline__ void passB_tail(float (&v)[32], float* lds,
                                           const uint32_t t, const uint32_t bb,
                                           const float* __restrict__ trig,
                                           float* __restrict__ state)
{
  const float2* cs = (const float2*)(trig + 50 * L);
  // R0: dims 0..4. Element o <-> address bb|(t<<5)|o.
#pragma unroll
  for (int j = 0; j < 5; ++j) {
    const float2 w = cs[j];
    const float c = w.x, s = w.y;
    const uint32_t mu = MK.M[L][j];            // within bits 0..4
    const uint32_t fj = MK.F[L][j];
    const float se = (__builtin_popcount((bb | (t << 5)) & fj) & 1) ? -s : s;
#pragma unroll
    for (uint32_t o = 0; o < 32; ++o) {
      if (__builtin_popcount(o & fj & 31u) & 1) continue;   // compile-time
      const uint32_t o2 = o ^ mu;
      const float a0 = v[o], a1 = v[o2];
      v[o]  = c * a0 - se * a1;
      v[o2] = c * a1 + se * a0;
    }
  }
  // exchange 1: write own segment (b128, cswz layout)
  {
    float4* l4 = (float4*)lds;
#pragma unroll
    for (uint32_t k = 0; k < 8; ++k) {
      float4 q = { v[4*k], v[4*k+1], v[4*k+2], v[4*k+3] };
      l4[cswz((t << 5) + 4u * k) >> 2] = q;
    }
  }
  __syncthreads();
  // R1: dims 5..9; thread coords: dims 0..4 <- t bits 0..4, dims 10..14 <- t bits 5..9
  uint32_t B1 = 0u;
#pragma unroll
  for (int i = 0; i < 5; ++i) B1 ^= ((t >> i) & 1u) ? MK.M[L][i] : 0u;
#pragma unroll
  for (int i = 0; i < 5; ++i) B1 ^= ((t >> (5 + i)) & 1u) ? MK.M[L][10 + i] : 0u;
  const uint32_t B1s = cswz(B1);
#pragma unroll
  for (uint32_t y = 0; y < 32; ++y) v[y] = lds[B1s ^ cswz(kxorB(L, 5, y))];
#pragma unroll
  for (int j = 0; j < 5; ++j) {
    const float2 w = cs[5 + j];
    const float c = w.x, s = w.y;
    const float se = (__builtin_popcount(bb & MK.F[L][5 + j]) & 1) ? -s : s;
#pragma unroll
    for (uint32_t y = 0; y < 32; ++y) {
      if ((y >> j) & 1u) continue;
      const uint32_t y2 = y | (1u << j);
      const float a0 = v[y], a1 = v[y2];
      v[y]  = c * a0 - se * a1;
      v[y2] = c * a1 + se * a0;
    }
  }
  __syncthreads();   // protect re-write of same slots
#pragma unroll
  for (uint32_t y = 0; y < 32; ++y) lds[B1s ^ cswz(kxorB(L, 5, y))] = v[y];
  __syncthreads();
  // R2: dims 10..14; thread coords: dims 0..4 <- t bits 0..4, dims 5..9 <- t bits 5..9
  uint32_t B2 = 0u;
#pragma unroll
  for (int i = 0; i < 5; ++i) B2 ^= ((t >> i) & 1u) ? MK.M[L][i] : 0u;
#pragma unroll
  for (int i = 0; i < 5; ++i) B2 ^= ((t >> (5 + i)) & 1u) ? MK.M[L][5 + i] : 0u;
  const uint32_t B2s = cswz(B2);
#pragma unroll
  for (uint32_t y = 0; y < 32; ++y) v[y] = lds[B2s ^ cswz(kxorB(L, 10, y))];
  __syncthreads();   // LDS free for next tile after this point
#pragma unroll
  for (int j = 0; j < 5; ++j) {
    const float2 w = cs[10 + j];
    const float c = w.x, s = w.y;
    const float se = (__builtin_popcount(bb & MK.F[L][10 + j]) & 1) ? -s : s;
#pragma unroll
    for (uint32_t y = 0; y < 32; ++y) {
      if ((y >> j) & 1u) continue;
      const uint32_t y2 = y | (1u << j);
      const float a0 = v[y], a1 = v[y2];
      v[y]  = c * a0 - se * a1;
      v[y2] = c * a1 + se * a0;
    }
  }
  // direct store: per inst, each 32-lane phase covers one 128B segment
#pragma unroll
  for (uint32_t y = 0; y < 32; ++y) state[bb ^ B2 ^ kxorB(L, 10, y)] = v[y];
}

template<int L>
__global__ __launch_bounds__(1024, 4) void kpassB(float* __restrict__ state,
                                                  const float* __restrict__ trig)
{
  __shared__ __align__(16) float lds[32768];
  const uint32_t t = threadIdx.x;
  float u[32];
  {
    const float4* g4 = (const float4*)(state + ((uint32_t)blockIdx.x << 15) + (t << 5));
#pragma unroll
    for (uint32_t k = 0; k < 8; ++k) {
      float4 q = g4[k];
      u[4*k] = q.x; u[4*k+1] = q.y; u[4*k+2] = q.z; u[4*k+3] = q.w;
    }
  }
#pragma unroll
  for (uint32_t it = 0; it < 4; ++it) {
    const uint32_t bb = ((uint32_t)blockIdx.x + 256u * it) << 15;
    float v[32];
#pragma unroll
    for (int k = 0; k < 32; ++k) v[k] = u[k];
    if (it < 3) {   // prefetch next tile: overlaps all exchange/compute phases
      const float4* g4 = (const float4*)(state + (((uint32_t)blockIdx.x + 256u * (it + 1)) << 15) + (t << 5));
#pragma unroll
      for (uint32_t k = 0; k < 8; ++k) {
        float4 q = g4[k];
        u[4*k] = q.x; u[4*k+1] = q.y; u[4*k+2] = q.z; u[4*k+3] = q.w;
      }
    }
    passB_tail<L>(v, lds, t, bb, trig, state);
  }
}

// kinit: layer-0 product state built analytically in tile-address order
// (62 mults), then layer-1 passB tail. Write-only pass, 4 tiles/block.
__global__ __launch_bounds__(1024, 4) void kinit(float* __restrict__ state,
                                                 const float* __restrict__ trig)
{
  __shared__ __align__(16) float lds[32768];
  const uint32_t t = threadIdx.x;
  const float2* cs0 = (const float2*)trig;       // layer 0, indexed by bit
#pragma unroll
  for (uint32_t it = 0; it < 4; ++it) {
    const uint32_t bb = ((uint32_t)blockIdx.x + 256u * it) << 15;
    const uint32_t hi = bb | (t << 5);
    float pt = 1.0f;
#pragma unroll
    for (int b = 5; b < 25; ++b) {
      const float2 w = cs0[b];
      pt *= ((hi >> b) & 1u) ? w.y : w.x;
    }
    float v[32];
    v[0] = pt;
#pragma unroll
    for (int j = 0; j < 5; ++j) {
      const float2 w = cs0[j];
#pragma unroll
      for (int o = 0; o < (1 << j); ++o) {
        v[o | (1 << j)] = v[o] * w.y;
        v[o]            = v[o] * w.x;
      }
    }
    passB_tail<1>(v, lds, t, bb, trig, state);
  }
}

// ---- passA: pivots 15..24. Block = 32 contiguous spectators (slo) x 1024
// combos; 4 cosets per block with prefetch. One LDS exchange per coset.
template<int L, bool FIN>
__global__ __launch_bounds__(1024, 4) void kpassA(float* __restrict__ state,
                                                  const float* __restrict__ trig,
                                                  float* __restrict__ outp)
{
  __shared__ __align__(16) float lds[32768];
  __shared__ float wsum[16];
  const uint32_t t = threadIdx.x;
  const float2* cs = (const float2*)(trig + 50 * L) + 15;
  const uint32_t slo = t & 31u;
  const uint32_t yf  = t >> 5;
  uint32_t cy = 0u;      // R0 combo part (pivots 20..24 from yf)
#pragma unroll
  for (int k = 0; k < 5; ++k) cy ^= ((yf >> k) & 1u) ? MK.M[L][20 + k] : 0u;
  uint32_t cumt = 0u;    // R1 combo part (pivots 15..19 from yf)
#pragma unroll
  for (int k = 0; k < 5; ++k) cumt ^= ((yf >> k) & 1u) ? MK.M[L][15 + k] : 0u;

  float u[32];
  {
    const uint32_t A0 = ((uint32_t)blockIdx.x << 5) ^ slo ^ cy;
#pragma unroll
    for (uint32_t x = 0; x < 32; ++x) u[x] = state[A0 ^ kxorB(L, 15, x)];
  }
  float facc = 0.0f;
#pragma unroll
  for (uint32_t it = 0; it < 4; ++it) {
    const uint32_t sbase = ((uint32_t)blockIdx.x + 256u * it) << 5;
    float v[32];
#pragma unroll
    for (int k = 0; k < 32; ++k) v[k] = u[k];
    if (it < 3) {   // prefetch next coset's gathers
      const uint32_t A0 = (((uint32_t)blockIdx.x + 256u * (it + 1)) << 5) ^ slo ^ cy;
#pragma unroll
      for (uint32_t x = 0; x < 32; ++x) u[x] = state[A0 ^ kxorB(L, 15, x)];
    }
    // R0: register dims = pivots 15..19
#pragma unroll
    for (int j = 0; j < 5; ++j) {
      const float2 w = cs[j];
      const float c = w.x, s = w.y;
#pragma unroll
      for (uint32_t x = 0; x < 32; ++x) {
        if ((x >> j) & 1u) continue;
        const uint32_t x2 = x | (1u << j);
        const float a0 = v[x], a1 = v[x2];
        v[x]  = c * a0 - s * a1;
        v[x2] = s * a0 + c * a1;
      }
    }
    // exchange: slot = (yf<<10)|(x<<5)|slo, swizzled (low5 ^= bits 5..9)
#pragma unroll
    for (uint32_t x = 0; x < 32; ++x) {
      const uint32_t la = (yf << 10) + (x << 5) + slo;
      lds[la ^ ((la >> 5) & 31u)] = v[x];
    }
    __syncthreads();
    // R1: register dims = pivots 20..24
    const uint32_t Ab = sbase ^ slo ^ cumt;
    {
      const uint32_t labase = (yf << 5) + slo;
      uint32_t la = labase ^ ((labase >> 5) & 31u);
      v[0] = lds[la];
#pragma unroll
      for (int k = 1; k < 32; ++k) {
        la ^= 1u << (10 + __builtin_ctz((unsigned)k));
        v[k ^ (k >> 1)] = lds[la];
      }
    }
    __syncthreads();   // LDS free for next coset
#pragma unroll
    for (int j = 0; j < 5; ++j) {
      const float2 w = cs[5 + j];
      const float c = w.x, s = w.y;
#pragma unroll
      for (uint32_t x = 0; x < 32; ++x) {
        if ((x >> j) & 1u) continue;
        const uint32_t x2 = x | (1u << j);
        const float a0 = v[x], a1 = v[x2];
        v[x]  = c * a0 - s * a1;
        v[x2] = s * a0 + c * a1;
      }
    }
    if (!FIN) {
      uint32_t a = Ab;
      state[a] = v[0];
#pragma unroll
      for (int k = 1; k < 32; ++k) {
        a ^= MK.M[L][20 + __builtin_ctz((unsigned)k)];
        state[a] = v[k ^ (k >> 1)];
      }
    } else {
      constexpr uint32_t pz =
          (cpar(MK.M[L][20] & MK.fz) << 0) | (cpar(MK.M[L][21] & MK.fz) << 1) |
          (cpar(MK.M[L][22] & MK.fz) << 2) | (cpar(MK.M[L][23] & MK.fz) << 3) |
          (cpar(MK.M[L][24] & MK.fz) << 4);
      float acc = 0.0f;
#pragma unroll
      for (uint32_t x = 0; x < 32; ++x) {
        const float q = v[x] * v[x];
        acc += cpar(x & pz) ? -q : q;
      }
      if (__builtin_popcount(Ab & MK.fz) & 1) acc = -acc;
      facc += acc;
    }
  }
  if (FIN) {
#pragma unroll
    for (int off = 32; off >= 1; off >>= 1) facc += __shfl_down(facc, off, 64);
    if ((t & 63u) == 0u) wsum[t >> 6] = facc;
    __syncthreads();
    if (t == 0) {
      float ssum = 0.0f;
#pragma unroll
      for (int w2 = 0; w2 < 16; ++w2) ssum += wsum[w2];
      atomicAdd(outp, ssum);
    }
  }
}

extern "C" void kernel_launch(void* const* d_in, const int* in_sizes, int n_in,
                              void* d_out, int out_size, void* d_ws, size_t ws_size,
                              hipStream_t stream)
{
  (void)in_sizes; (void)n_in; (void)out_size; (void)ws_size;
  const float* theta = (const float*)d_in[0];
  float* outp  = (float*)d_out;
  float* state = (float*)d_ws;                                    // 2^25 floats
  float* trig  = (float*)((char*)d_ws + (size_t)(1u << 25) * 4u); // 400 floats

  kprep<<<1, 256, 0, stream>>>(theta, trig, outp);
  kinit<<<256, 1024, 0, stream>>>(state, trig);
  kpassA<1, false><<<256, 1024, 0, stream>>>(state, trig, outp);
  kpassB<2><<<256, 1024, 0, stream>>>(state, trig);
  kpassA<2, false><<<256, 1024, 0, stream>>>(state, trig, outp);
  kpassB<3><<<256, 1024, 0, stream>>>(state, trig);
  kpassA<3, false><<<256, 1024, 0, stream>>>(state, trig, outp);
  kpassB<4><<<256, 1024, 0, stream>>>(state, trig);
  kpassA<4, false><<<256, 1024, 0, stream>>>(state, trig, outp);
  kpassB<5><<<256, 1024, 0, stream>>>(state, trig);
  kpassA<5, false><<<256, 1024, 0, stream>>>(state, trig, outp);
  kpassB<6><<<256, 1024, 0, stream>>>(state, trig);
  kpassA<6, false><<<256, 1024, 0, stream>>>(state, trig, outp);
  kpassB<7><<<256, 1024, 0, stream>>>(state, trig);
  kpassA<7, true><<<256, 1024, 0, stream>>>(state, trig, outp);
}

// Round 5
// 723.233 us; speedup vs baseline: 1.3707x; 1.3707x over previous
//
#include <hip/hip_runtime.h>
#include <hip/hip_fp16.h>
#include <stdint.h>

// 25-qubit, 8-layer RY + CNOT-chain circuit, output <Z_q0>.
// CNOT chains deferred into a GF(2) change-of-basis; only 200 RYs touch the
// state. Round 5: state stored as fp16 (2^25 halves = 64 MiB -> fully
// L3-resident; HBM traffic collapses). All arithmetic and LDS exchanges stay
// f32; only 13 fp16 quantization events (round-to-nearest, unbiased).
// Stores merge bit-0 memory pairs across lanes (partner lane = t^1 since
// M[L][0]=e0 for every layer) -> full-dword predicated stores, no sub-dword
// write granularity. Structure otherwise = round 3 (grid 1024, 1 tile/block;
// cross-block overlap comes from CU block turnover).

#define NQ 25
#define DEPTH 8

struct MaskSet {
  uint32_t M[DEPTH][NQ];   // M[l][b] = column b of W_l (pairing masks)
  uint32_t F[DEPTH][NQ];   // F[l][b] = row b of W_l^-1 (orientation functionals)
  uint32_t fz;             // final Z functional (row 24 of W_8^-1)
};

__host__ __device__ constexpr MaskSet buildMasks() {
  MaskSet r{};
  uint32_t col[NQ] = {}, inv[NQ] = {};
  for (int j = 0; j < NQ; ++j) { col[j] = 1u << j; inv[j] = 1u << j; }
  for (int l = 0; l < DEPTH; ++l) {
    for (int b = 0; b < NQ; ++b) { r.M[l][b] = col[b]; r.F[l][b] = inv[b]; }
    for (int w = 0; w < NQ - 1; ++w) {   // CNOT chain of layer l
      const int cb = 24 - w, tb = 23 - w;
      col[cb] ^= col[tb];
      inv[tb] ^= inv[cb];
    }
  }
  r.fz = inv[24];
  return r;
}

constexpr MaskSet MK = buildMasks();

__host__ __device__ constexpr uint32_t cswz(uint32_t a) { return a ^ ((a >> 3) & 28u); }

__host__ __device__ constexpr uint32_t kxorB(int L, int d0, uint32_t y) {
  uint32_t a = 0;
  for (int i = 0; i < 5; ++i) if ((y >> i) & 1u) a ^= MK.M[L][d0 + i];
  return a;
}

__host__ __device__ constexpr uint32_t cpar(uint32_t x) {
  uint32_t p = 0;
  for (int i = 0; i < 32; ++i) p ^= (x >> i) & 1u;
  return p;
}

// Evenness functional for R2's low-bit: bit0 of B2(t) = parity(t & r2mask(L)).
__host__ __device__ constexpr uint32_t r2mask(int L) {
  uint32_t r = 0;
  for (int i = 0; i < 5; ++i) {
    r |= (MK.M[L][i] & 1u) << i;         // t bits 0..4 -> dims 0..4
    r |= (MK.M[L][5 + i] & 1u) << (5 + i); // t bits 5..9 -> dims 5..9
  }
  return r;
}

__device__ __forceinline__ uint32_t pkh(float a, float b) {
  __half2 h = __floats2half2_rn(a, b);   // round-to-nearest (unbiased)
  return __builtin_bit_cast(uint32_t, h);
}
__device__ __forceinline__ float2 uph(uint32_t w) {
  __half2 h = __builtin_bit_cast(__half2, w);
  return __half22float2(h);
}
__device__ __forceinline__ float h2f(uint16_t x) {
  __half h = __builtin_bit_cast(__half, x);
  return __half2float(h);
}

__global__ void kprep(const float* __restrict__ theta, float* __restrict__ trig,
                      float* __restrict__ outp)
{
  int t = threadIdx.x;
  if (t == 0) outp[0] = 0.0f;
  if (t < 200) {
    int l = t / 25, b = t % 25;            // b = bit position, qubit w = 24-b
    float th = theta[l * 25 + (24 - b)] * 0.5f;
    trig[2 * t]     = cosf(th);
    trig[2 * t + 1] = sinf(th);
  }
}

// ---- passB tail: R0 (dims 0..4, v in tile-address order) -> LDS -> R1 ->
//      LDS -> R2 -> packed fp16 global store.
template<int L>
__device__ __forceinline__ void passB_tail(float (&v)[32], float* lds,
                                           const uint32_t t, const uint32_t bb,
                                           const float* __restrict__ trig,
                                           uint16_t* __restrict__ stateH)
{
  const float2* cs = (const float2*)(trig + 50 * L);
  // R0: dims 0..4. Element o <-> address bb|(t<<5)|o.
#pragma unroll
  for (int j = 0; j < 5; ++j) {
    const float2 w = cs[j];
    const float c = w.x, s = w.y;
    const uint32_t mu = MK.M[L][j];            // within bits 0..4
    const uint32_t fj = MK.F[L][j];
    const float se = (__builtin_popcount((bb | (t << 5)) & fj) & 1) ? -s : s;
#pragma unroll
    for (uint32_t o = 0; o < 32; ++o) {
      if (__builtin_popcount(o & fj & 31u) & 1) continue;   // compile-time
      const uint32_t o2 = o ^ mu;
      const float a0 = v[o], a1 = v[o2];
      v[o]  = c * a0 - se * a1;
      v[o2] = c * a1 + se * a0;
    }
  }
  // exchange 1: write own segment (b128, cswz layout, f32)
  {
    float4* l4 = (float4*)lds;
#pragma unroll
    for (uint32_t k = 0; k < 8; ++k) {
      float4 q = { v[4*k], v[4*k+1], v[4*k+2], v[4*k+3] };
      l4[cswz((t << 5) + 4u * k) >> 2] = q;
    }
  }
  __syncthreads();
  // R1: dims 5..9; thread coords: dims 0..4 <- t bits 0..4, dims 10..14 <- t bits 5..9
  uint32_t B1 = 0u;
#pragma unroll
  for (int i = 0; i < 5; ++i) B1 ^= ((t >> i) & 1u) ? MK.M[L][i] : 0u;
#pragma unroll
  for (int i = 0; i < 5; ++i) B1 ^= ((t >> (5 + i)) & 1u) ? MK.M[L][10 + i] : 0u;
  const uint32_t B1s = cswz(B1);
#pragma unroll
  for (uint32_t y = 0; y < 32; ++y) v[y] = lds[B1s ^ cswz(kxorB(L, 5, y))];
#pragma unroll
  for (int j = 0; j < 5; ++j) {
    const float2 w = cs[5 + j];
    const float c = w.x, s = w.y;
    const float se = (__builtin_popcount(bb & MK.F[L][5 + j]) & 1) ? -s : s;
#pragma unroll
    for (uint32_t y = 0; y < 32; ++y) {
      if ((y >> j) & 1u) continue;
      const uint32_t y2 = y | (1u << j);
      const float a0 = v[y], a1 = v[y2];
      v[y]  = c * a0 - se * a1;
      v[y2] = c * a1 + se * a0;
    }
  }
  __syncthreads();   // protect re-write of same slots
#pragma unroll
  for (uint32_t y = 0; y < 32; ++y) lds[B1s ^ cswz(kxorB(L, 5, y))] = v[y];
  __syncthreads();
  // R2: dims 10..14; thread coords: dims 0..4 <- t bits 0..4, dims 5..9 <- t bits 5..9
  uint32_t B2 = 0u;
#pragma unroll
  for (int i = 0; i < 5; ++i) B2 ^= ((t >> i) & 1u) ? MK.M[L][i] : 0u;
#pragma unroll
  for (int i = 0; i < 5; ++i) B2 ^= ((t >> (5 + i)) & 1u) ? MK.M[L][5 + i] : 0u;
  const uint32_t B2s = cswz(B2);
#pragma unroll
  for (uint32_t y = 0; y < 32; ++y) v[y] = lds[B2s ^ cswz(kxorB(L, 10, y))];
#pragma unroll
  for (int j = 0; j < 5; ++j) {
    const float2 w = cs[10 + j];
    const float c = w.x, s = w.y;
    const float se = (__builtin_popcount(bb & MK.F[L][10 + j]) & 1) ? -s : s;
#pragma unroll
    for (uint32_t y = 0; y < 32; ++y) {
      if ((y >> j) & 1u) continue;
      const uint32_t y2 = y | (1u << j);
      const float a0 = v[y], a1 = v[y2];
      v[y]  = c * a0 - se * a1;
      v[y2] = c * a1 + se * a0;
    }
  }
  // packed store: lanes (t, t^1) hold memory-adjacent elements (M[L][0]=e0);
  // even-address lanes (parity(t & r2mask)==0) store one dword = 2 halves.
  // Masks 10..14 never touch bit 0 (band [b-7,b], b>=10), so pairing holds
  // for every y. Each 32-lane phase: 16 active lanes x 4B = full 64B segs.
  {
    constexpr uint32_t rm = r2mask(L);
    const bool ev = (__builtin_popcount(t & rm) & 1) == 0;
#pragma unroll
    for (uint32_t y = 0; y < 32; ++y) {
      const float p = __shfl_xor(v[y], 1, 64);
      if (ev) {
        const uint32_t ad = bb ^ B2 ^ kxorB(L, 10, y);   // even address
        *(uint32_t*)(stateH + ad) = pkh(v[y], p);
      }
    }
  }
}

template<int L>
__global__ __launch_bounds__(1024, 4) void kpassB(uint16_t* __restrict__ stateH,
                                                  const float* __restrict__ trig)
{
  __shared__ __align__(16) float lds[32768];
  const uint32_t t = threadIdx.x;
  const uint32_t bb = (uint32_t)blockIdx.x << 15;
  // direct load: thread t owns 64 contiguous bytes (32 halves, tile order)
  float v[32];
  {
    const uint4* g4 = (const uint4*)(stateH + bb + (t << 5));
#pragma unroll
    for (uint32_t k = 0; k < 4; ++k) {
      const uint4 q = g4[k];
      float2 f;
      f = uph(q.x); v[8*k+0] = f.x; v[8*k+1] = f.y;
      f = uph(q.y); v[8*k+2] = f.x; v[8*k+3] = f.y;
      f = uph(q.z); v[8*k+4] = f.x; v[8*k+5] = f.y;
      f = uph(q.w); v[8*k+6] = f.x; v[8*k+7] = f.y;
    }
  }
  passB_tail<L>(v, lds, t, bb, trig, stateH);
}

// kinit: layer-0 product state built analytically in tile-address order
// (62 mults), then layer-1 passB tail. Write-only pass.
__global__ __launch_bounds__(1024, 4) void kinit(uint16_t* __restrict__ stateH,
                                                 const float* __restrict__ trig)
{
  __shared__ __align__(16) float lds[32768];
  const uint32_t t = threadIdx.x;
  const uint32_t bb = (uint32_t)blockIdx.x << 15;
  const float2* cs0 = (const float2*)trig;       // layer 0, indexed by bit
  const uint32_t hi = bb | (t << 5);
  float pt = 1.0f;
#pragma unroll
  for (int b = 5; b < 25; ++b) {
    const float2 w = cs0[b];
    pt *= ((hi >> b) & 1u) ? w.y : w.x;
  }
  float v[32];
  v[0] = pt;
#pragma unroll
  for (int j = 0; j < 5; ++j) {
    const float2 w = cs0[j];
#pragma unroll
    for (int o = 0; o < (1 << j); ++o) {
      v[o | (1 << j)] = v[o] * w.y;
      v[o]            = v[o] * w.x;
    }
  }
  passB_tail<1>(v, lds, t, bb, trig, stateH);
}

// ---- passA: pivots 15..24. Block = 32 contiguous spectators (slo) x 1024
// combos. Gather loads (64B/inst-half), one f32 LDS exchange, packed stores.
template<int L, bool FIN>
__global__ __launch_bounds__(1024, 4) void kpassA(uint16_t* __restrict__ stateH,
                                                  const float* __restrict__ trig,
                                                  float* __restrict__ outp)
{
  __shared__ __align__(16) float lds[32768];
  __shared__ float wsum[16];
  const uint32_t t = threadIdx.x;
  const uint32_t sbase = (uint32_t)blockIdx.x << 5;   // bits 5..14
  const float2* cs = (const float2*)(trig + 50 * L) + 15;
  const uint32_t slo = t & 31u;
  const uint32_t yf  = t >> 5;
  // R0: register dims = pivots 15..19; yf -> pivots 20..24.
  uint32_t cy = 0u;
#pragma unroll
  for (int k = 0; k < 5; ++k) cy ^= ((yf >> k) & 1u) ? MK.M[L][20 + k] : 0u;
  const uint32_t A0 = sbase ^ slo ^ cy;
  float v[32];
#pragma unroll
  for (uint32_t x = 0; x < 32; ++x) v[x] = h2f(stateH[A0 ^ kxorB(L, 15, x)]);
#pragma unroll
  for (int j = 0; j < 5; ++j) {
    const float2 w = cs[j];
    const float c = w.x, s = w.y;
#pragma unroll
    for (uint32_t x = 0; x < 32; ++x) {
      if ((x >> j) & 1u) continue;
      const uint32_t x2 = x | (1u << j);
      const float a0 = v[x], a1 = v[x2];
      v[x]  = c * a0 - s * a1;
      v[x2] = s * a0 + c * a1;
    }
  }
  // exchange: slot = (yf<<10)|(x<<5)|slo, swizzled (low5 ^= bits 5..9), f32
#pragma unroll
  for (uint32_t x = 0; x < 32; ++x) {
    const uint32_t la = (yf << 10) + (x << 5) + slo;
    lds[la ^ ((la >> 5) & 31u)] = v[x];
  }
  __syncthreads();
  // R1: register dims = pivots 20..24; yf -> pivots 15..19.
  uint32_t cumt = 0u;
#pragma unroll
  for (int k = 0; k < 5; ++k) cumt ^= ((yf >> k) & 1u) ? MK.M[L][15 + k] : 0u;
  const uint32_t Ab = sbase ^ slo ^ cumt;
  {
    const uint32_t labase = (yf << 5) + slo;
    uint32_t la = labase ^ ((labase >> 5) & 31u);
    v[0] = lds[la];
#pragma unroll
    for (int k = 1; k < 32; ++k) {
      la ^= 1u << (10 + __builtin_ctz((unsigned)k));
      v[k ^ (k >> 1)] = lds[la];
    }
  }
#pragma unroll
  for (int j = 0; j < 5; ++j) {
    const float2 w = cs[5 + j];
    const float c = w.x, s = w.y;
#pragma unroll
    for (uint32_t x = 0; x < 32; ++x) {
      if ((x >> j) & 1u) continue;
      const uint32_t x2 = x | (1u << j);
      const float a0 = v[x], a1 = v[x2];
      v[x]  = c * a0 - s * a1;
      v[x2] = s * a0 + c * a1;
    }
  }
  if (!FIN) {
    // packed store: bit 0 of addr = t&1 (masks 15..24 never touch bit 0);
    // partner lane = t^1; even lanes store dwords.
    const bool ev = (t & 1u) == 0u;
#pragma unroll
    for (uint32_t x = 0; x < 32; ++x) {
      const float p = __shfl_xor(v[x], 1, 64);
      if (ev) {
        const uint32_t ad = Ab ^ kxorB(L, 20, x);        // even address
        *(uint32_t*)(stateH + ad) = pkh(v[x], p);
      }
    }
  } else {
    constexpr uint32_t pz =
        (cpar(MK.M[L][20] & MK.fz) << 0) | (cpar(MK.M[L][21] & MK.fz) << 1) |
        (cpar(MK.M[L][22] & MK.fz) << 2) | (cpar(MK.M[L][23] & MK.fz) << 3) |
        (cpar(MK.M[L][24] & MK.fz) << 4);
    float acc = 0.0f;
#pragma unroll
    for (uint32_t x = 0; x < 32; ++x) {
      const float q = v[x] * v[x];
      acc += cpar(x & pz) ? -q : q;
    }
    if (__builtin_popcount(Ab & MK.fz) & 1) acc = -acc;
#pragma unroll
    for (int off = 32; off >= 1; off >>= 1) acc += __shfl_down(acc, off, 64);
    if ((t & 63u) == 0u) wsum[t >> 6] = acc;
    __syncthreads();
    if (t == 0) {
      float ssum = 0.0f;
#pragma unroll
      for (int w2 = 0; w2 < 16; ++w2) ssum += wsum[w2];
      atomicAdd(outp, ssum);
    }
  }
}

extern "C" void kernel_launch(void* const* d_in, const int* in_sizes, int n_in,
                              void* d_out, int out_size, void* d_ws, size_t ws_size,
                              hipStream_t stream)
{
  (void)in_sizes; (void)n_in; (void)out_size; (void)ws_size;
  const float* theta = (const float*)d_in[0];
  float* outp  = (float*)d_out;
  uint16_t* stateH = (uint16_t*)d_ws;                              // 2^25 halves
  float* trig  = (float*)((char*)d_ws + (size_t)(1u << 25) * 2u);  // 400 floats

  kprep<<<1, 256, 0, stream>>>(theta, trig, outp);
  kinit<<<1024, 1024, 0, stream>>>(stateH, trig);
  kpassA<1, false><<<1024, 1024, 0, stream>>>(stateH, trig, outp);
  kpassB<2><<<1024, 1024, 0, stream>>>(stateH, trig);
  kpassA<2, false><<<1024, 1024, 0, stream>>>(stateH, trig, outp);
  kpassB<3><<<1024, 1024, 0, stream>>>(stateH, trig);
  kpassA<3, false><<<1024, 1024, 0, stream>>>(stateH, trig, outp);
  kpassB<4><<<1024, 1024, 0, stream>>>(stateH, trig);
  kpassA<4, false><<<1024, 1024, 0, stream>>>(stateH, trig, outp);
  kpassB<5><<<1024, 1024, 0, stream>>>(stateH, trig);
  kpassA<5, false><<<1024, 1024, 0, stream>>>(stateH, trig, outp);
  kpassB<6><<<1024, 1024, 0, stream>>>(stateH, trig);
  kpassA<6, false><<<1024, 1024, 0, stream>>>(stateH, trig, outp);
  kpassB<7><<<1024, 1024, 0, stream>>>(stateH, trig);
  kpassA<7, true><<<1024, 1024, 0, stream>>>(stateH, trig, outp);
}

// Round 6
// 718.206 us; speedup vs baseline: 1.3803x; 1.0070x over previous
//
#include <hip/hip_runtime.h>
#include <hip/hip_fp16.h>
#include <stdint.h>

// 25-qubit, 8-layer RY + CNOT-chain circuit, output <Z_q0>.
// CNOT chains deferred into a GF(2) change-of-basis; only 200 RYs touch the
// state (2^25 fp16 = 64 MiB in d_ws). All arithmetic/LDS exchanges in f32.
// Round 6: full-wave memory instructions via lane-pairing. Bit 0 of every
// global address equals t&1 (kpassA) / parity(t&rm) (kpassB), and partner
// lane is always t^1 (M[L][0]=e0). So gathers/stores process (x, x^1) pairs:
// even-class lanes handle the even-x dword, odd-class the odd-x dword, one
// shfl_xor(1) redistributes halves -> 16 unpredicated 64-lane dword insts
// (256B payload) replacing 32 half-payload/half-predicated ones.

#define NQ 25
#define DEPTH 8

struct MaskSet {
  uint32_t M[DEPTH][NQ];   // M[l][b] = column b of W_l (pairing masks)
  uint32_t F[DEPTH][NQ];   // F[l][b] = row b of W_l^-1 (orientation functionals)
  uint32_t fz;             // final Z functional (row 24 of W_8^-1)
};

__host__ __device__ constexpr MaskSet buildMasks() {
  MaskSet r{};
  uint32_t col[NQ] = {}, inv[NQ] = {};
  for (int j = 0; j < NQ; ++j) { col[j] = 1u << j; inv[j] = 1u << j; }
  for (int l = 0; l < DEPTH; ++l) {
    for (int b = 0; b < NQ; ++b) { r.M[l][b] = col[b]; r.F[l][b] = inv[b]; }
    for (int w = 0; w < NQ - 1; ++w) {   // CNOT chain of layer l
      const int cb = 24 - w, tb = 23 - w;
      col[cb] ^= col[tb];
      inv[tb] ^= inv[cb];
    }
  }
  r.fz = inv[24];
  return r;
}

constexpr MaskSet MK = buildMasks();

__host__ __device__ constexpr uint32_t cswz(uint32_t a) { return a ^ ((a >> 3) & 28u); }

__host__ __device__ constexpr uint32_t kxorB(int L, int d0, uint32_t y) {
  uint32_t a = 0;
  for (int i = 0; i < 5; ++i) if ((y >> i) & 1u) a ^= MK.M[L][d0 + i];
  return a;
}

__host__ __device__ constexpr uint32_t cpar(uint32_t x) {
  uint32_t p = 0;
  for (int i = 0; i < 32; ++i) p ^= (x >> i) & 1u;
  return p;
}

// Evenness functional for R2's low-bit: bit0 of B2(t) = parity(t & r2mask(L)).
__host__ __device__ constexpr uint32_t r2mask(int L) {
  uint32_t r = 0;
  for (int i = 0; i < 5; ++i) {
    r |= (MK.M[L][i] & 1u) << i;           // t bits 0..4 -> dims 0..4
    r |= (MK.M[L][5 + i] & 1u) << (5 + i); // t bits 5..9 -> dims 5..9
  }
  return r;
}

__device__ __forceinline__ uint32_t pkh(float a, float b) {
  __half2 h = __floats2half2_rn(a, b);   // round-to-nearest (unbiased)
  return __builtin_bit_cast(uint32_t, h);
}
__device__ __forceinline__ float2 uph(uint32_t w) {
  __half2 h = __builtin_bit_cast(__half2, w);
  return __half22float2(h);
}
__device__ __forceinline__ float h2fu(uint32_t x) {   // low 16 bits -> f32
  __half h = __builtin_bit_cast(__half, (uint16_t)(x & 0xffffu));
  return __half2float(h);
}

__global__ void kprep(const float* __restrict__ theta, float* __restrict__ trig,
                      float* __restrict__ outp)
{
  int t = threadIdx.x;
  if (t == 0) outp[0] = 0.0f;
  if (t < 200) {
    int l = t / 25, b = t % 25;            // b = bit position, qubit w = 24-b
    float th = theta[l * 25 + (24 - b)] * 0.5f;
    trig[2 * t]     = cosf(th);
    trig[2 * t + 1] = sinf(th);
  }
}

// ---- passB tail: R0 (dims 0..4, v in tile-address order) -> LDS -> R1 ->
//      LDS -> R2 -> merged full-wave fp16 dword stores.
template<int L>
__device__ __forceinline__ void passB_tail(float (&v)[32], float* lds,
                                           const uint32_t t, const uint32_t bb,
                                           const float* __restrict__ trig,
                                           uint16_t* __restrict__ stateH)
{
  const float2* cs = (const float2*)(trig + 50 * L);
  // R0: dims 0..4. Element o <-> address bb|(t<<5)|o.
#pragma unroll
  for (int j = 0; j < 5; ++j) {
    const float2 w = cs[j];
    const float c = w.x, s = w.y;
    const uint32_t mu = MK.M[L][j];            // within bits 0..4
    const uint32_t fj = MK.F[L][j];
    const float se = (__builtin_popcount((bb | (t << 5)) & fj) & 1) ? -s : s;
#pragma unroll
    for (uint32_t o = 0; o < 32; ++o) {
      if (__builtin_popcount(o & fj & 31u) & 1) continue;   // compile-time
      const uint32_t o2 = o ^ mu;
      const float a0 = v[o], a1 = v[o2];
      v[o]  = c * a0 - se * a1;
      v[o2] = c * a1 + se * a0;
    }
  }
  // exchange 1: write own segment (b128, cswz layout, f32)
  {
    float4* l4 = (float4*)lds;
#pragma unroll
    for (uint32_t k = 0; k < 8; ++k) {
      float4 q = { v[4*k], v[4*k+1], v[4*k+2], v[4*k+3] };
      l4[cswz((t << 5) + 4u * k) >> 2] = q;
    }
  }
  __syncthreads();
  // R1: dims 5..9; thread coords: dims 0..4 <- t bits 0..4, dims 10..14 <- t bits 5..9
  uint32_t B1 = 0u;
#pragma unroll
  for (int i = 0; i < 5; ++i) B1 ^= ((t >> i) & 1u) ? MK.M[L][i] : 0u;
#pragma unroll
  for (int i = 0; i < 5; ++i) B1 ^= ((t >> (5 + i)) & 1u) ? MK.M[L][10 + i] : 0u;
  const uint32_t B1s = cswz(B1);
#pragma unroll
  for (uint32_t y = 0; y < 32; ++y) v[y] = lds[B1s ^ cswz(kxorB(L, 5, y))];
#pragma unroll
  for (int j = 0; j < 5; ++j) {
    const float2 w = cs[5 + j];
    const float c = w.x, s = w.y;
    const float se = (__builtin_popcount(bb & MK.F[L][5 + j]) & 1) ? -s : s;
#pragma unroll
    for (uint32_t y = 0; y < 32; ++y) {
      if ((y >> j) & 1u) continue;
      const uint32_t y2 = y | (1u << j);
      const float a0 = v[y], a1 = v[y2];
      v[y]  = c * a0 - se * a1;
      v[y2] = c * a1 + se * a0;
    }
  }
  __syncthreads();   // protect re-write of same slots
#pragma unroll
  for (uint32_t y = 0; y < 32; ++y) lds[B1s ^ cswz(kxorB(L, 5, y))] = v[y];
  __syncthreads();
  // R2: dims 10..14; thread coords: dims 0..4 <- t bits 0..4, dims 5..9 <- t bits 5..9
  uint32_t B2 = 0u;
#pragma unroll
  for (int i = 0; i < 5; ++i) B2 ^= ((t >> i) & 1u) ? MK.M[L][i] : 0u;
#pragma unroll
  for (int i = 0; i < 5; ++i) B2 ^= ((t >> (5 + i)) & 1u) ? MK.M[L][5 + i] : 0u;
  const uint32_t B2s = cswz(B2);
#pragma unroll
  for (uint32_t y = 0; y < 32; ++y) v[y] = lds[B2s ^ cswz(kxorB(L, 10, y))];
#pragma unroll
  for (int j = 0; j < 5; ++j) {
    const float2 w = cs[10 + j];
    const float c = w.x, s = w.y;
    const float se = (__builtin_popcount(bb & MK.F[L][10 + j]) & 1) ? -s : s;
#pragma unroll
    for (uint32_t y = 0; y < 32; ++y) {
      if ((y >> j) & 1u) continue;
      const uint32_t y2 = y | (1u << j);
      const float a0 = v[y], a1 = v[y2];
      v[y]  = c * a0 - se * a1;
      v[y2] = c * a1 + se * a0;
    }
  }
  // merged store: pair (y, y^1) via M[L][10] (no bit-0 component, L<=7).
  // cls = bit0 of own address = parity(t & rm); partner lane = t^1 (M[L][0]=e0).
  // cls=0 lanes store the even-y dword, cls=1 lanes the odd-y dword:
  // one unpredicated 64-lane dword store per pair = 2 full 128B lines.
  {
    constexpr uint32_t rm = r2mask(L);
    const uint32_t cls = (uint32_t)__builtin_popcount(t & rm) & 1u;
    const uint32_t sb = bb ^ B2;
#pragma unroll
    for (uint32_t yp = 0; yp < 32; yp += 2) {
      const float p0 = __shfl_xor(v[yp], 1, 64);
      const float p1 = __shfl_xor(v[yp + 1], 1, 64);
      const uint32_t ad = (sb ^ kxorB(L, 10, yp) ^ (cls ? MK.M[L][10] : 0u)) & ~1u;
      const uint32_t val = cls ? pkh(p1, v[yp + 1]) : pkh(v[yp], p0);
      *(uint32_t*)(stateH + ad) = val;
    }
  }
}

template<int L>
__global__ __launch_bounds__(1024, 4) void kpassB(uint16_t* __restrict__ stateH,
                                                  const float* __restrict__ trig)
{
  __shared__ __align__(16) float lds[32768];
  const uint32_t t = threadIdx.x;
  const uint32_t bb = (uint32_t)blockIdx.x << 15;
  // direct load: thread t owns 64 contiguous bytes (32 halves, tile order)
  float v[32];
  {
    const uint4* g4 = (const uint4*)(stateH + bb + (t << 5));
#pragma unroll
    for (uint32_t k = 0; k < 4; ++k) {
      const uint4 q = g4[k];
      float2 f;
      f = uph(q.x); v[8*k+0] = f.x; v[8*k+1] = f.y;
      f = uph(q.y); v[8*k+2] = f.x; v[8*k+3] = f.y;
      f = uph(q.z); v[8*k+4] = f.x; v[8*k+5] = f.y;
      f = uph(q.w); v[8*k+6] = f.x; v[8*k+7] = f.y;
    }
  }
  passB_tail<L>(v, lds, t, bb, trig, stateH);
}

// kinit: layer-0 product state built analytically in tile-address order
// (62 mults), then layer-1 passB tail. Write-only pass.
__global__ __launch_bounds__(1024, 4) void kinit(uint16_t* __restrict__ stateH,
                                                 const float* __restrict__ trig)
{
  __shared__ __align__(16) float lds[32768];
  const uint32_t t = threadIdx.x;
  const uint32_t bb = (uint32_t)blockIdx.x << 15;
  const float2* cs0 = (const float2*)trig;       // layer 0, indexed by bit
  const uint32_t hi = bb | (t << 5);
  float pt = 1.0f;
#pragma unroll
  for (int b = 5; b < 25; ++b) {
    const float2 w = cs0[b];
    pt *= ((hi >> b) & 1u) ? w.y : w.x;
  }
  float v[32];
  v[0] = pt;
#pragma unroll
  for (int j = 0; j < 5; ++j) {
    const float2 w = cs0[j];
#pragma unroll
    for (int o = 0; o < (1 << j); ++o) {
      v[o | (1 << j)] = v[o] * w.y;
      v[o]            = v[o] * w.x;
    }
  }
  passB_tail<1>(v, lds, t, bb, trig, stateH);
}

// ---- passA: pivots 15..24. Block = 32 contiguous spectators (slo) x 1024
// combos. Merged dword gathers/stores (lane-pairing), one f32 LDS exchange.
// All passA masks live in bits >= 8, so address bit 0 = t&1 throughout.
template<int L, bool FIN>
__global__ __launch_bounds__(1024, 4) void kpassA(uint16_t* __restrict__ stateH,
                                                  const float* __restrict__ trig,
                                                  float* __restrict__ outp)
{
  __shared__ __align__(16) float lds[32768];
  __shared__ float wsum[16];
  const uint32_t t = threadIdx.x;
  const uint32_t sbase = (uint32_t)blockIdx.x << 5;   // bits 5..14
  const float2* cs = (const float2*)(trig + 50 * L) + 15;
  const uint32_t slo = t & 31u;
  const uint32_t yf  = t >> 5;
  const uint32_t odd = t & 1u;
  // R0: register dims = pivots 15..19; yf -> pivots 20..24.
  uint32_t cy = 0u;
#pragma unroll
  for (int k = 0; k < 5; ++k) cy ^= ((yf >> k) & 1u) ? MK.M[L][20 + k] : 0u;
  const uint32_t A0 = sbase ^ slo ^ cy;
  float v[32];
  // merged gathers: pair (x, x^1) via M[L][15]. Even lanes load the x-dword
  // (own slo pair), odd lanes the x^1-dword; shfl_xor(1) redistributes.
#pragma unroll
  for (uint32_t xp = 0; xp < 32; xp += 2) {
    const uint32_t ax = (A0 ^ kxorB(L, 15, xp) ^ (odd ? MK.M[L][15] : 0u)) & ~1u;
    const uint32_t d  = *(const uint32_t*)(stateH + ax);
    const uint32_t dp = __shfl_xor(d, 1, 64);
    // even lane: own d = x-dword (low = own slo), dp = x^1-dword
    // odd  lane: own d = x^1-dword (high = own slo), dp = x-dword
    v[xp]     = h2fu(odd ? (dp >> 16) : d);
    v[xp + 1] = h2fu(odd ? (d >> 16)  : dp);
  }
#pragma unroll
  for (int j = 0; j < 5; ++j) {
    const float2 w = cs[j];
    const float c = w.x, s = w.y;
#pragma unroll
    for (uint32_t x = 0; x < 32; ++x) {
      if ((x >> j) & 1u) continue;
      const uint32_t x2 = x | (1u << j);
      const float a0 = v[x], a1 = v[x2];
      v[x]  = c * a0 - s * a1;
      v[x2] = s * a0 + c * a1;
    }
  }
  // exchange: slot = (yf<<10)|(x<<5)|slo, swizzled (low5 ^= bits 5..9), f32
#pragma unroll
  for (uint32_t x = 0; x < 32; ++x) {
    const uint32_t la = (yf << 10) + (x << 5) + slo;
    lds[la ^ ((la >> 5) & 31u)] = v[x];
  }
  __syncthreads();
  // R1: register dims = pivots 20..24; yf -> pivots 15..19.
  uint32_t cumt = 0u;
#pragma unroll
  for (int k = 0; k < 5; ++k) cumt ^= ((yf >> k) & 1u) ? MK.M[L][15 + k] : 0u;
  const uint32_t Ab = sbase ^ slo ^ cumt;
  {
    const uint32_t labase = (yf << 5) + slo;
    uint32_t la = labase ^ ((labase >> 5) & 31u);
    v[0] = lds[la];
#pragma unroll
    for (int k = 1; k < 32; ++k) {
      la ^= 1u << (10 + __builtin_ctz((unsigned)k));
      v[k ^ (k >> 1)] = lds[la];
    }
  }
#pragma unroll
  for (int j = 0; j < 5; ++j) {
    const float2 w = cs[5 + j];
    const float c = w.x, s = w.y;
#pragma unroll
    for (uint32_t x = 0; x < 32; ++x) {
      if ((x >> j) & 1u) continue;
      const uint32_t x2 = x | (1u << j);
      const float a0 = v[x], a1 = v[x2];
      v[x]  = c * a0 - s * a1;
      v[x2] = s * a0 + c * a1;
    }
  }
  if (!FIN) {
    // merged stores: pair (x, x^1) via M[L][20]; even lanes store x-dword,
    // odd lanes x^1-dword; one unpredicated 64-lane store per pair.
#pragma unroll
    for (uint32_t xp = 0; xp < 32; xp += 2) {
      const float p0 = __shfl_xor(v[xp], 1, 64);
      const float p1 = __shfl_xor(v[xp + 1], 1, 64);
      const uint32_t ad = (Ab ^ kxorB(L, 20, xp) ^ (odd ? MK.M[L][20] : 0u)) & ~1u;
      const uint32_t val = odd ? pkh(p1, v[xp + 1]) : pkh(v[xp], p0);
      *(uint32_t*)(stateH + ad) = val;
    }
  } else {
    constexpr uint32_t pz =
        (cpar(MK.M[L][20] & MK.fz) << 0) | (cpar(MK.M[L][21] & MK.fz) << 1) |
        (cpar(MK.M[L][22] & MK.fz) << 2) | (cpar(MK.M[L][23] & MK.fz) << 3) |
        (cpar(MK.M[L][24] & MK.fz) << 4);
    float acc = 0.0f;
#pragma unroll
    for (uint32_t x = 0; x < 32; ++x) {
      const float q = v[x] * v[x];
      acc += cpar(x & pz) ? -q : q;
    }
    if (__builtin_popcount(Ab & MK.fz) & 1) acc = -acc;
#pragma unroll
    for (int off = 32; off >= 1; off >>= 1) acc += __shfl_down(acc, off, 64);
    if ((t & 63u) == 0u) wsum[t >> 6] = acc;
    __syncthreads();
    if (t == 0) {
      float ssum = 0.0f;
#pragma unroll
      for (int w2 = 0; w2 < 16; ++w2) ssum += wsum[w2];
      atomicAdd(outp, ssum);
    }
  }
}

extern "C" void kernel_launch(void* const* d_in, const int* in_sizes, int n_in,
                              void* d_out, int out_size, void* d_ws, size_t ws_size,
                              hipStream_t stream)
{
  (void)in_sizes; (void)n_in; (void)out_size; (void)ws_size;
  const float* theta = (const float*)d_in[0];
  float* outp  = (float*)d_out;
  uint16_t* stateH = (uint16_t*)d_ws;                              // 2^25 halves
  float* trig  = (float*)((char*)d_ws + (size_t)(1u << 25) * 2u);  // 400 floats

  kprep<<<1, 256, 0, stream>>>(theta, trig, outp);
  kinit<<<1024, 1024, 0, stream>>>(stateH, trig);
  kpassA<1, false><<<1024, 1024, 0, stream>>>(stateH, trig, outp);
  kpassB<2><<<1024, 1024, 0, stream>>>(stateH, trig);
  kpassA<2, false><<<1024, 1024, 0, stream>>>(stateH, trig, outp);
  kpassB<3><<<1024, 1024, 0, stream>>>(stateH, trig);
  kpassA<3, false><<<1024, 1024, 0, stream>>>(stateH, trig, outp);
  kpassB<4><<<1024, 1024, 0, stream>>>(stateH, trig);
  kpassA<4, false><<<1024, 1024, 0, stream>>>(stateH, trig, outp);
  kpassB<5><<<1024, 1024, 0, stream>>>(stateH, trig);
  kpassA<5, false><<<1024, 1024, 0, stream>>>(stateH, trig, outp);
  kpassB<6><<<1024, 1024, 0, stream>>>(stateH, trig);
  kpassA<6, false><<<1024, 1024, 0, stream>>>(stateH, trig, outp);
  kpassB<7><<<1024, 1024, 0, stream>>>(stateH, trig);
  kpassA<7, true><<<1024, 1024, 0, stream>>>(stateH, trig, outp);
}